// Round 11
// baseline (95.189 us; speedup 1.0000x reference)
//
#include <hip/hip_runtime.h>

#define NROWS 16384
#define OBSD 512
#define ENCD 512
#define ACTD 64
#define KEXP 8

typedef __attribute__((ext_vector_type(8))) short bf16x8;
typedef __attribute__((ext_vector_type(4))) float f32x4;
typedef __attribute__((address_space(3))) unsigned char lds_byte;
typedef __attribute__((address_space(1))) unsigned char glb_byte;

__device__ __forceinline__ unsigned short f2bf(float f) {
  unsigned int u = __float_as_uint(f);
  u = (u + 0x7FFFu + ((u >> 16) & 1u)) >> 16;
  return (unsigned short)u;
}
__device__ __forceinline__ unsigned int cvtpk(float lo, float hi) {
  unsigned int r;
  asm("v_cvt_pk_bf16_f32 %0, %1, %2" : "=v"(r) : "v"(lo), "v"(hi));
  return r;
}
__device__ __forceinline__ void gload_lds16(const unsigned short* g, unsigned short* l) {
  __builtin_amdgcn_global_load_lds((const glb_byte*)g, (lds_byte*)l, 16, 0, 0);
}

// ---------------- gt_k: GT matrix + accumulator zeroing (64 blocks) --------
__global__ __launch_bounds__(256) void gt_k(
    const float* __restrict__ W, const float* __restrict__ Cw,
    float* __restrict__ GT, float* __restrict__ loss,
    int* __restrict__ counts, int* __restrict__ cursor) {
  const int b = blockIdx.x, tid = threadIdx.x;
  if (b == 0) {
    if (tid == 0) *loss = 0.f;
    if (tid < KEXP) { counts[tid] = 0; cursor[tid] = 0; }
  }
  __shared__ float red[4][64];
  int e = b >> 3, o0 = (b & 7) * 64;
  int o = tid & 63, hg = tid >> 6;
  float s = 0.f;
#pragma unroll 8
  for (int h = hg * 128; h < hg * 128 + 128; h++)
    s += Cw[e * ENCD + h] * W[(size_t)h * OBSD + o0 + o];
  red[hg][o] = s;
  __syncthreads();
  if (tid < 64)
    GT[(o0 + tid) * KEXP + e] = red[0][tid] + red[1][tid] + red[2][tid] + red[3][tid];
}

// ---------------- fused_prep: routing+X0cvt, X1cvt, -BfT, U/W/-A converts --
// NOTE: A and BfT are stored NEGATED so grouped's MFMA accumulates X1e - pred.
__global__ __launch_bounds__(256) void fused_prep_k(
    const float* __restrict__ X0, const float* __restrict__ X1,
    const float* __restrict__ U, const float* __restrict__ W,
    const float* __restrict__ Aall, const float* __restrict__ Brest,
    const float* __restrict__ GT, const float* __restrict__ Cb,
    unsigned short* __restrict__ X0bf, unsigned short* __restrict__ X1bf,
    unsigned short* __restrict__ Ubf, unsigned short* __restrict__ Wbf,
    unsigned short* __restrict__ AbfN, unsigned short* __restrict__ BfTN,
    int* __restrict__ inds, int* __restrict__ counts) {
  const int b = blockIdx.x, tid = threadIdx.x;
  if (b < 512) {  // routing + X0 convert
    __shared__ int lhist[KEXP];
    if (tid < KEXP) lhist[tid] = 0;
    __syncthreads();
    const int lane = tid & 63, w = tid >> 6;
    float g[8][8];
    const float* gp = GT + lane * 8 * KEXP;
#pragma unroll
    for (int j = 0; j < 8; j++) {
      float4 lo = *(const float4*)(gp + j * KEXP);
      float4 hi = *(const float4*)(gp + j * KEXP + 4);
      g[j][0] = lo.x; g[j][1] = lo.y; g[j][2] = lo.z; g[j][3] = lo.w;
      g[j][4] = hi.x; g[j][5] = hi.y; g[j][6] = hi.z; g[j][7] = hi.w;
    }
    float cb[KEXP];
#pragma unroll
    for (int e = 0; e < KEXP; e++) cb[e] = Cb[e];
#pragma unroll 2
    for (int r = 0; r < 8; r++) {
      const int n = b * 32 + w * 8 + r;
      const float4* xr = (const float4*)(X0 + (size_t)n * OBSD + lane * 8);
      float4 x = xr[0], y = xr[1];
      float xv[8] = {x.x, x.y, x.z, x.w, y.x, y.y, y.z, y.w};
      float acc[KEXP] = {};
#pragma unroll
      for (int j = 0; j < 8; j++)
#pragma unroll
        for (int e = 0; e < KEXP; e++) acc[e] += xv[j] * g[j][e];
      uint4 rr = {cvtpk(x.x, x.y), cvtpk(x.z, x.w), cvtpk(y.x, y.y), cvtpk(y.z, y.w)};
      *(uint4*)&X0bf[(size_t)n * OBSD + lane * 8] = rr;
#pragma unroll
      for (int e = 0; e < KEXP; e++) {
#pragma unroll
        for (int off = 32; off > 0; off >>= 1) acc[e] += __shfl_xor(acc[e], off, 64);
      }
      if (lane == 0) {
        int best = 0;
        float bv = acc[0] + cb[0];
#pragma unroll
        for (int e = 1; e < KEXP; e++) {
          float v = acc[e] + cb[e];
          if (v > bv) { bv = v; best = e; }  // strict >: first max wins (jnp.argmax)
        }
        inds[n] = best;
        atomicAdd(&lhist[best], 1);
      }
    }
    __syncthreads();
    if (tid < KEXP) atomicAdd(&counts[tid], lhist[tid]);
    return;
  }
  if (b < 4608) {  // dense X1 convert
    size_t i = ((size_t)(b - 512) * 256 + tid) * 8;
    const float4* s4 = (const float4*)(X1 + i);
    float4 a = s4[0], c = s4[1];
    uint4 r = {cvtpk(a.x, a.y), cvtpk(a.z, a.w), cvtpk(c.x, c.y), cvtpk(c.z, c.w)};
    *(uint4*)&X1bf[i] = r;
    return;
  }
  if (b < 4664) {  // -BfT transpose for experts 1..7
    __shared__ float tile[64][65];
    int t = b - 4608;
    int k = (t >> 3);
    int e0 = (t & 7) * 64;
    const float* src = Brest + (size_t)k * ACTD * ENCD + e0;
#pragma unroll
    for (int j = 0; j < 16; j++) {
      int idx = j * 256 + tid;
      int a = idx >> 6, e = idx & 63;
      tile[a][e] = src[(size_t)a * ENCD + e];
    }
    __syncthreads();
    unsigned short* dst = BfTN + ((size_t)(k + 1) * ENCD + e0) * ACTD;
#pragma unroll
    for (int j = 0; j < 16; j++) {
      int idx = j * 256 + tid;
      int e = idx >> 6, a = idx & 63;
      dst[(size_t)e * ACTD + a] = f2bf(-tile[a][e]);   // negated
    }
    return;
  }
  if (b == 4664) {  // expert-0: -identity  (-1.0 bf16 = 0xBF80)
    for (int j = 0; j < 16; j++) {
      int i8 = j * 256 + tid;
      int e = i8 >> 3, a0 = (i8 & 7) * 8;
      unsigned int w0 = 0, w1 = 0, w2 = 0, w3 = 0;
      if (e >= a0 && e < a0 + 8) {
        unsigned int bits = 0xBF80u << ((e & 1) * 16);
        if ((e - a0) >> 1 == 0) w0 = bits;
        else if ((e - a0) >> 1 == 1) w1 = bits;
        else if ((e - a0) >> 1 == 2) w2 = bits;
        else w3 = bits;
      }
      uint4 v = {w0, w1, w2, w3};
      *(uint4*)&BfTN[(size_t)i8 * 8] = v;
    }
    return;
  }
  // dense converts: U [4665,5689), W [5689,5945), -A [5945,7993)
  int cb2 = b - 4665;
  if (cb2 < 1024) {
    size_t i = (size_t)cb2 * 256 + tid;
    float4 v = ((const float4*)U)[i];
    uint2 r = {cvtpk(v.x, v.y), cvtpk(v.z, v.w)};
    *(uint2*)&Ubf[i * 4] = r;
  } else if (cb2 < 1280) {
    size_t i = (size_t)(cb2 - 1024) * 256 + tid;
    float4 v = ((const float4*)W)[i];
    uint2 r = {cvtpk(v.x, v.y), cvtpk(v.z, v.w)};
    *(uint2*)&Wbf[i * 4] = r;
  } else {
    size_t i = (size_t)(cb2 - 1280) * 256 + tid;
    float4 v = ((const float4*)Aall)[i];
    uint2 r = {cvtpk(-v.x, -v.y), cvtpk(-v.z, -v.w)};  // negated
    *(uint2*)&AbfN[i * 4] = r;
  }
}

// ---------------- encoder MFMA (X0e only, BK=64) + scatter tail ------------
// blocks [0,512):   X0e = X0bf @ Wbf^T (round-10 verified structure)
// blocks [512,576): scatter with per-block local prefix from counts
__global__ __launch_bounds__(256, 2) void enc_scatter_k(
    const unsigned short* __restrict__ X0bf, const unsigned short* __restrict__ Wbf,
    unsigned short* __restrict__ X0e, const int* __restrict__ inds,
    const int* __restrict__ counts, int* __restrict__ cursor,
    int* __restrict__ rowlist) {
  if (blockIdx.x >= 512) {  // scatter
    __shared__ int lhist[KEXP], lbase[KEXP], sstart[KEXP];
    const int tid = threadIdx.x;
    if (tid < KEXP) {
      lhist[tid] = 0;
      int s = 0;
      for (int j = 0; j < KEXP; j++) {  // local prefix (counts ready)
        if (j == tid) sstart[tid] = s;
        s += counts[j];
      }
    }
    __syncthreads();
    const int n = (blockIdx.x - 512) * 256 + tid;
    const int r = inds[n];
    const int lpos = atomicAdd(&lhist[r], 1);
    __syncthreads();
    if (tid < KEXP) lbase[tid] = atomicAdd(&cursor[tid], lhist[tid]);
    __syncthreads();
    rowlist[sstart[r] + lbase[r] + lpos] = n;
    return;
  }
  __shared__ unsigned short As[128 * 64];
  __shared__ unsigned short Bs[128 * 64];
  const int tid = threadIdx.x;
  const int bid = blockIdx.x;  // 512 enc blocks, %8==0 -> bijective XCD swizzle
  const int lid = (bid & 7) * 64 + (bid >> 3);
  const int col0 = (lid & 3) * 128;
  const int row0 = (lid >> 2) * 128;

  const int lane = tid & 63, w = tid >> 6;
  const int wr = w >> 1, wc = w & 1;
  const int srow8 = tid >> 3;
  const int lslot = ((tid & 7) ^ (srow8 & 7)) * 8;
  const int ldsoff = tid * 8;
  const int r15 = lane & 15;
  const int qk = lane >> 4;
  const int rsw = r15 & 7;
  const int arow = wr * 64 + r15;
  const int brow = wc * 64 + r15;

  f32x4 acc[4][4] = {};
  for (int k0 = 0; k0 < OBSD; k0 += 64) {
#pragma unroll
    for (int j = 0; j < 4; j++) {
      int row = j * 32 + srow8;
      gload_lds16(X0bf + (size_t)(row0 + row) * OBSD + k0 + lslot, &As[j * 2048 + ldsoff]);
      gload_lds16(Wbf + (size_t)(col0 + row) * OBSD + k0 + lslot, &Bs[j * 2048 + ldsoff]);
    }
    __syncthreads();
#pragma unroll
    for (int kk = 0; kk < 2; kk++) {
      const int ps = ((kk * 4 + qk) ^ rsw) * 8;
      bf16x8 af[4], bfr[4];
#pragma unroll
      for (int m = 0; m < 4; m++) af[m] = *(const bf16x8*)&As[(arow + m * 16) * 64 + ps];
#pragma unroll
      for (int n = 0; n < 4; n++) bfr[n] = *(const bf16x8*)&Bs[(brow + n * 16) * 64 + ps];
#pragma unroll
      for (int m = 0; m < 4; m++)
#pragma unroll
        for (int n = 0; n < 4; n++)
          acc[m][n] = __builtin_amdgcn_mfma_f32_16x16x32_bf16(bfr[n], af[m], acc[m][n], 0, 0, 0);
    }
    __syncthreads();
  }
#pragma unroll
  for (int m = 0; m < 4; m++) {
    int rowg = row0 + wr * 64 + m * 16 + r15;
#pragma unroll
    for (int n = 0; n < 4; n++) {
      int colg = col0 + wc * 64 + n * 16 + qk * 4;
      uint2 v = {cvtpk(acc[m][n][0], acc[m][n][1]), cvtpk(acc[m][n][2], acc[m][n][3])};
      *(uint2*)&X0e[(size_t)rowg * ENCD + colg] = v;
    }
  }
}

// ---------------- grouped MFMA v3: 2-phase pipelined, acc = X1e - pred -----
// 17 BK=64 tiles: t<8 X1@W, t<16 X0e@(-A), t=16 U@(-BfT). Double-buffered
// LDS; stage(t+1) issued BEFORE compute(t); explicit vmcnt(0) drain before
// the single barrier per tile (r5 NaN suspect: compiler not draining the
// global_load_lds builtin before __syncthreads).
__global__ __launch_bounds__(256, 2) void grouped_mfma_k(
    const unsigned short* __restrict__ X1bf, const unsigned short* __restrict__ X0ebf,
    const unsigned short* __restrict__ Wbf, const unsigned short* __restrict__ Ubf,
    const unsigned short* __restrict__ AbfN, const unsigned short* __restrict__ BfTN,
    const int* __restrict__ rowlist, const int* __restrict__ counts,
    float* __restrict__ loss) {
  const int tid = threadIdx.x;
  const int bid = blockIdx.x;  // 4096 blocks
  const int lid = (bid & 7) * 512 + (bid >> 3);
  const int k = lid >> 9;
  const int rem = lid & 511;
  const int col0 = (rem & 3) * 128;
  const int tile = rem >> 2;

  int start = 0, cnt = 0;
#pragma unroll
  for (int j = 0; j < KEXP; j++) {  // local prefix from counts
    int c = counts[j];
    if (j < k) start += c;
    if (j == k) cnt = c;
  }
  if (tile * 128 >= cnt) return;

  __shared__ unsigned short As[2][128 * 64];  // 32 KB
  __shared__ unsigned short Bs[2][128 * 64];  // 32 KB
  __shared__ int ridx[128];
  __shared__ float red[4];

  if (tid < 128) {
    int p = tile * 128 + tid;
    ridx[tid] = rowlist[start + (p < cnt ? p : 0)];
  }
  __syncthreads();

  const int lane = tid & 63, w = tid >> 6;
  const int wr = w >> 1, wc = w & 1;
  const int srow8 = tid >> 3;
  const int lslot = ((tid & 7) ^ (srow8 & 7)) * 8;
  const int ldsoff = tid * 8;
  const int r15 = lane & 15;
  const int qk = lane >> 4;
  const int rsw = r15 & 7;
  const int arow = wr * 64 + r15;
  const int brow = wc * 64 + r15;
  int rnj[4];
#pragma unroll
  for (int j = 0; j < 4; j++) rnj[j] = ridx[j * 32 + srow8];

  const unsigned short* AkN = AbfN + (size_t)k * ENCD * ENCD;
  const unsigned short* BfTkN = BfTN + (size_t)k * ENCD * ACTD;

  auto stage = [&](int t, int buf) {
    unsigned short* as = &As[buf][0];
    unsigned short* bs = &Bs[buf][0];
    if (t < 8) {
      int k0 = t * 64;
#pragma unroll
      for (int j = 0; j < 4; j++) {
        int row = j * 32 + srow8;
        gload_lds16(X1bf + (size_t)rnj[j] * OBSD + k0 + lslot, &as[j * 2048 + ldsoff]);
        gload_lds16(Wbf + (size_t)(col0 + row) * OBSD + k0 + lslot, &bs[j * 2048 + ldsoff]);
      }
    } else if (t < 16) {
      int k0 = (t - 8) * 64;
#pragma unroll
      for (int j = 0; j < 4; j++) {
        int row = j * 32 + srow8;
        gload_lds16(X0ebf + (size_t)rnj[j] * ENCD + k0 + lslot, &as[j * 2048 + ldsoff]);
        gload_lds16(AkN + (size_t)(col0 + row) * ENCD + k0 + lslot, &bs[j * 2048 + ldsoff]);
      }
    } else {
#pragma unroll
      for (int j = 0; j < 4; j++) {
        int row = j * 32 + srow8;
        gload_lds16(Ubf + (size_t)rnj[j] * ACTD + lslot, &as[j * 2048 + ldsoff]);
        gload_lds16(BfTkN + (size_t)(col0 + row) * ACTD + lslot, &bs[j * 2048 + ldsoff]);
      }
    }
  };

  f32x4 acc[4][4] = {};
  auto compute = [&](int buf) {
    const unsigned short* as = &As[buf][0];
    const unsigned short* bs = &Bs[buf][0];
#pragma unroll
    for (int kk = 0; kk < 2; kk++) {
      const int ps = ((kk * 4 + qk) ^ rsw) * 8;
      bf16x8 af[4], bfr[4];
#pragma unroll
      for (int m = 0; m < 4; m++) af[m] = *(const bf16x8*)&as[(arow + m * 16) * 64 + ps];
#pragma unroll
      for (int n = 0; n < 4; n++) bfr[n] = *(const bf16x8*)&bs[(brow + n * 16) * 64 + ps];
#pragma unroll
      for (int m = 0; m < 4; m++)
#pragma unroll
        for (int n = 0; n < 4; n++)
          acc[m][n] = __builtin_amdgcn_mfma_f32_16x16x32_bf16(bfr[n], af[m], acc[m][n], 0, 0, 0);
    }
  };

  // prologue: fill buffer 0, drain, barrier
  stage(0, 0);
  asm volatile("s_waitcnt vmcnt(0)" ::: "memory");
  __syncthreads();
#pragma unroll 1
  for (int t = 0; t < 17; ++t) {
    const int cur = t & 1;
    if (t < 16) stage(t + 1, cur ^ 1);      // loads in flight under MFMA
    compute(cur);
    asm volatile("s_waitcnt vmcnt(0)" ::: "memory");  // next buffer landed
    __syncthreads();                         // single barrier per tile
  }

  // epilogue: acc holds X1e - pred; sum of squares over valid rows
  float sq = 0.f;
#pragma unroll
  for (int m = 0; m < 4; m++) {
    int lr = wr * 64 + m * 16 + r15;
    if (tile * 128 + lr < cnt) {
#pragma unroll
      for (int n = 0; n < 4; n++)
        sq += acc[m][n][0] * acc[m][n][0] + acc[m][n][1] * acc[m][n][1] +
              acc[m][n][2] * acc[m][n][2] + acc[m][n][3] * acc[m][n][3];
    }
  }
#pragma unroll
  for (int off = 32; off > 0; off >>= 1) sq += __shfl_xor(sq, off, 64);
  if (lane == 0) red[w] = sq;
  __syncthreads();
  if (tid == 0) atomicAdd(loss, red[0] + red[1] + red[2] + red[3]);
}

__global__ void finalize_k(const float* __restrict__ loss, float* __restrict__ out) {
  if (threadIdx.x == 0 && blockIdx.x == 0)
    out[0] = loss[0] * (1.0f / ((float)ENCD * (float)NROWS));
}

extern "C" void kernel_launch(void* const* d_in, const int* in_sizes, int n_in,
                              void* d_out, int out_size, void* d_ws, size_t ws_size,
                              hipStream_t stream) {
  const float* X1 = (const float*)d_in[0];
  const float* X0 = (const float*)d_in[1];
  const float* U = (const float*)d_in[2];
  const float* W = (const float*)d_in[3];
  const float* Aall = (const float*)d_in[4];
  const float* Brest = (const float*)d_in[5];
  const float* Cw = (const float*)d_in[6];
  const float* Cb = (const float*)d_in[7];
  float* out = (float*)d_out;

  char* p = (char*)d_ws;
  auto alloc = [&](size_t bytes) { char* r = p; p += (bytes + 255) & ~(size_t)255; return r; };
  unsigned short* X1bf = (unsigned short*)alloc((size_t)NROWS * OBSD * 2);
  unsigned short* X0bf = (unsigned short*)alloc((size_t)NROWS * OBSD * 2);
  unsigned short* Ubf = (unsigned short*)alloc((size_t)NROWS * ACTD * 2);
  unsigned short* Wbf = (unsigned short*)alloc((size_t)ENCD * OBSD * 2);
  unsigned short* AbfN = (unsigned short*)alloc((size_t)KEXP * ENCD * ENCD * 2);
  unsigned short* BfTN = (unsigned short*)alloc((size_t)KEXP * ENCD * ACTD * 2);
  unsigned short* X0ebf = (unsigned short*)alloc((size_t)NROWS * ENCD * 2);
  float* GT = (float*)alloc(KEXP * OBSD * 4);
  float* loss = (float*)alloc(256);
  int* inds = (int*)alloc(NROWS * 4);
  int* rowlist = (int*)alloc(NROWS * 4);
  int* counts = (int*)alloc(64);
  int* cursor = (int*)alloc(64);

  gt_k<<<64, 256, 0, stream>>>(W, Cw, GT, loss, counts, cursor);
  fused_prep_k<<<7993, 256, 0, stream>>>(X0, X1, U, W, Aall, Brest, GT, Cb,
                                         X0bf, X1bf, Ubf, Wbf, AbfN, BfTN,
                                         inds, counts);
  enc_scatter_k<<<576, 256, 0, stream>>>(X0bf, Wbf, X0ebf, inds, counts,
                                         cursor, rowlist);
  grouped_mfma_k<<<4096, 256, 0, stream>>>(X1bf, X0ebf, Wbf, Ubf, AbfN, BfTN,
                                           rowlist, counts, loss);
  finalize_k<<<1, 64, 0, stream>>>(loss, out);
}

// Round 12
// 79.073 us; speedup vs baseline: 1.2038x; 1.2038x over previous
//
#include <hip/hip_runtime.h>

#define NROWS 16384
#define OBSD 512
#define ENCD 512
#define ACTD 64
#define KEXP 8

typedef __attribute__((ext_vector_type(8))) short bf16x8;
typedef __attribute__((ext_vector_type(4))) float f32x4;
typedef __attribute__((address_space(3))) unsigned char lds_byte;
typedef __attribute__((address_space(1))) unsigned char glb_byte;

__device__ __forceinline__ unsigned short f2bf(float f) {
  unsigned int u = __float_as_uint(f);
  u = (u + 0x7FFFu + ((u >> 16) & 1u)) >> 16;
  return (unsigned short)u;
}
__device__ __forceinline__ unsigned int cvtpk(float lo, float hi) {
  unsigned int r;
  asm("v_cvt_pk_bf16_f32 %0, %1, %2" : "=v"(r) : "v"(lo), "v"(hi));
  return r;
}
__device__ __forceinline__ void gload_lds16(const unsigned short* g, unsigned short* l) {
  __builtin_amdgcn_global_load_lds((const glb_byte*)g, (lds_byte*)l, 16, 0, 0);
}

// ---------------- gt_k: GT matrix + accumulator zeroing (64 blocks) --------
__global__ __launch_bounds__(256) void gt_k(
    const float* __restrict__ W, const float* __restrict__ Cw,
    float* __restrict__ GT, float* __restrict__ loss,
    int* __restrict__ counts, int* __restrict__ cursor) {
  const int b = blockIdx.x, tid = threadIdx.x;
  if (b == 0) {
    if (tid == 0) *loss = 0.f;
    if (tid < KEXP) { counts[tid] = 0; cursor[tid] = 0; }
  }
  __shared__ float red[4][64];
  int e = b >> 3, o0 = (b & 7) * 64;
  int o = tid & 63, hg = tid >> 6;
  float s = 0.f;
#pragma unroll 8
  for (int h = hg * 128; h < hg * 128 + 128; h++)
    s += Cw[e * ENCD + h] * W[(size_t)h * OBSD + o0 + o];
  red[hg][o] = s;
  __syncthreads();
  if (tid < 64)
    GT[(o0 + tid) * KEXP + e] = red[0][tid] + red[1][tid] + red[2][tid] + red[3][tid];
}

// ---------------- fused_prep: routing+X0cvt, X1cvt, -BfT, U/W/-A, W^T ------
// NOTE: A and BfT stored NEGATED so grouped's MFMA accumulates X1e - pred.
// b [0,512):      routing (4 waves x 8 rows, coalesced) + fused X0->bf16
// b [512,4608):   dense X1->bf16
// b [4608,4664):  -BfT transpose experts 1..7
// b 4664:         -BfT expert-0 (-identity)
// b [4665,5689):  U cvt   [5689,5945): W cvt   [5945,7993): -A cvt
// b [7993,8057):  W^T bf16 transpose (WbfT[o][h] = W[h][o])
__global__ __launch_bounds__(256) void fused_prep_k(
    const float* __restrict__ X0, const float* __restrict__ X1,
    const float* __restrict__ U, const float* __restrict__ W,
    const float* __restrict__ Aall, const float* __restrict__ Brest,
    const float* __restrict__ GT, const float* __restrict__ Cb,
    unsigned short* __restrict__ X0bf, unsigned short* __restrict__ X1bf,
    unsigned short* __restrict__ Ubf, unsigned short* __restrict__ Wbf,
    unsigned short* __restrict__ AbfN, unsigned short* __restrict__ BfTN,
    unsigned short* __restrict__ WbfT, int* __restrict__ inds,
    int* __restrict__ counts) {
  const int b = blockIdx.x, tid = threadIdx.x;
  if (b < 512) {  // routing + X0 convert
    __shared__ int lhist[KEXP];
    if (tid < KEXP) lhist[tid] = 0;
    __syncthreads();
    const int lane = tid & 63, w = tid >> 6;
    float g[8][8];
    const float* gp = GT + lane * 8 * KEXP;
#pragma unroll
    for (int j = 0; j < 8; j++) {
      float4 lo = *(const float4*)(gp + j * KEXP);
      float4 hi = *(const float4*)(gp + j * KEXP + 4);
      g[j][0] = lo.x; g[j][1] = lo.y; g[j][2] = lo.z; g[j][3] = lo.w;
      g[j][4] = hi.x; g[j][5] = hi.y; g[j][6] = hi.z; g[j][7] = hi.w;
    }
    float cb[KEXP];
#pragma unroll
    for (int e = 0; e < KEXP; e++) cb[e] = Cb[e];
#pragma unroll 2
    for (int r = 0; r < 8; r++) {
      const int n = b * 32 + w * 8 + r;
      const float4* xr = (const float4*)(X0 + (size_t)n * OBSD + lane * 8);
      float4 x = xr[0], y = xr[1];
      float xv[8] = {x.x, x.y, x.z, x.w, y.x, y.y, y.z, y.w};
      float acc[KEXP] = {};
#pragma unroll
      for (int j = 0; j < 8; j++)
#pragma unroll
        for (int e = 0; e < KEXP; e++) acc[e] += xv[j] * g[j][e];
      uint4 rr = {cvtpk(x.x, x.y), cvtpk(x.z, x.w), cvtpk(y.x, y.y), cvtpk(y.z, y.w)};
      *(uint4*)&X0bf[(size_t)n * OBSD + lane * 8] = rr;
#pragma unroll
      for (int e = 0; e < KEXP; e++) {
#pragma unroll
        for (int off = 32; off > 0; off >>= 1) acc[e] += __shfl_xor(acc[e], off, 64);
      }
      if (lane == 0) {
        int best = 0;
        float bv = acc[0] + cb[0];
#pragma unroll
        for (int e = 1; e < KEXP; e++) {
          float v = acc[e] + cb[e];
          if (v > bv) { bv = v; best = e; }  // strict >: first max wins (jnp.argmax)
        }
        inds[n] = best;
        atomicAdd(&lhist[best], 1);
      }
    }
    __syncthreads();
    if (tid < KEXP) atomicAdd(&counts[tid], lhist[tid]);
    return;
  }
  if (b < 4608) {  // dense X1 convert
    size_t i = ((size_t)(b - 512) * 256 + tid) * 8;
    const float4* s4 = (const float4*)(X1 + i);
    float4 a = s4[0], c = s4[1];
    uint4 r = {cvtpk(a.x, a.y), cvtpk(a.z, a.w), cvtpk(c.x, c.y), cvtpk(c.z, c.w)};
    *(uint4*)&X1bf[i] = r;
    return;
  }
  if (b < 4664) {  // -BfT transpose for experts 1..7
    __shared__ float tile[64][65];
    int t = b - 4608;
    int k = (t >> 3);
    int e0 = (t & 7) * 64;
    const float* src = Brest + (size_t)k * ACTD * ENCD + e0;
#pragma unroll
    for (int j = 0; j < 16; j++) {
      int idx = j * 256 + tid;
      int a = idx >> 6, e = idx & 63;
      tile[a][e] = src[(size_t)a * ENCD + e];
    }
    __syncthreads();
    unsigned short* dst = BfTN + ((size_t)(k + 1) * ENCD + e0) * ACTD;
#pragma unroll
    for (int j = 0; j < 16; j++) {
      int idx = j * 256 + tid;
      int e = idx >> 6, a = idx & 63;
      dst[(size_t)e * ACTD + a] = f2bf(-tile[a][e]);   // negated
    }
    return;
  }
  if (b == 4664) {  // expert-0: -identity  (-1.0 bf16 = 0xBF80)
    for (int j = 0; j < 16; j++) {
      int i8 = j * 256 + tid;
      int e = i8 >> 3, a0 = (i8 & 7) * 8;
      unsigned int w0 = 0, w1 = 0, w2 = 0, w3 = 0;
      if (e >= a0 && e < a0 + 8) {
        unsigned int bits = 0xBF80u << ((e & 1) * 16);
        if ((e - a0) >> 1 == 0) w0 = bits;
        else if ((e - a0) >> 1 == 1) w1 = bits;
        else if ((e - a0) >> 1 == 2) w2 = bits;
        else w3 = bits;
      }
      uint4 v = {w0, w1, w2, w3};
      *(uint4*)&BfTN[(size_t)i8 * 8] = v;
    }
    return;
  }
  if (b < 7993) {  // dense converts: U [4665,5689), W [5689,5945), -A [5945,7993)
    int cb2 = b - 4665;
    if (cb2 < 1024) {
      size_t i = (size_t)cb2 * 256 + tid;
      float4 v = ((const float4*)U)[i];
      uint2 r = {cvtpk(v.x, v.y), cvtpk(v.z, v.w)};
      *(uint2*)&Ubf[i * 4] = r;
    } else if (cb2 < 1280) {
      size_t i = (size_t)(cb2 - 1024) * 256 + tid;
      float4 v = ((const float4*)W)[i];
      uint2 r = {cvtpk(v.x, v.y), cvtpk(v.z, v.w)};
      *(uint2*)&Wbf[i * 4] = r;
    } else {
      size_t i = (size_t)(cb2 - 1280) * 256 + tid;
      float4 v = ((const float4*)Aall)[i];
      uint2 r = {cvtpk(-v.x, -v.y), cvtpk(-v.z, -v.w)};  // negated
      *(uint2*)&AbfN[i * 4] = r;
    }
    return;
  }
  // W^T transpose: WbfT[o][h] = W[h][o]  (64x64 tiles, 8x8 grid)
  {
    __shared__ float tile[64][65];
    int t = b - 7993;
    int h0 = (t >> 3) * 64, o0 = (t & 7) * 64;
#pragma unroll
    for (int j = 0; j < 16; j++) {
      int idx = j * 256 + tid;
      int a = idx >> 6, e = idx & 63;      // a = h offset, e = o offset
      tile[a][e] = W[(size_t)(h0 + a) * OBSD + o0 + e];
    }
    __syncthreads();
#pragma unroll
    for (int j = 0; j < 16; j++) {
      int idx = j * 256 + tid;
      int e = idx >> 6, a = idx & 63;      // e = o offset, a = h offset
      WbfT[(size_t)(o0 + e) * OBSD + h0 + a] = f2bf(tile[a][e]);
    }
  }
}

// ---------------- scatter + M GEMM (one launch after prep) -----------------
// blocks [0,64):    scatter rows into rowlist (local prefix from counts)
// blocks [64,192):  M_kN = (-A_k) @ W  via AbfN x WbfT, 128x128 tiles.
//                   M_kN[e'][o] = sum_h (-A)[k][e'][h] * W[h][o]
__global__ __launch_bounds__(256, 2) void scatmgemm_k(
    const int* __restrict__ inds, const int* __restrict__ counts,
    int* __restrict__ cursor, int* __restrict__ rowlist,
    const unsigned short* __restrict__ AbfN, const unsigned short* __restrict__ WbfT,
    unsigned short* __restrict__ MN) {
  if (blockIdx.x < 64) {  // scatter
    __shared__ int lhist[KEXP], lbase[KEXP], sstart[KEXP];
    const int tid = threadIdx.x;
    if (tid < KEXP) {
      lhist[tid] = 0;
      int s = 0;
      for (int j = 0; j < KEXP; j++) {
        if (j == tid) sstart[tid] = s;
        s += counts[j];
      }
    }
    __syncthreads();
    const int n = blockIdx.x * 256 + tid;
    const int r = inds[n];
    const int lpos = atomicAdd(&lhist[r], 1);
    __syncthreads();
    if (tid < KEXP) lbase[tid] = atomicAdd(&cursor[tid], lhist[tid]);
    __syncthreads();
    rowlist[sstart[r] + lbase[r] + lpos] = n;
    return;
  }
  // M GEMM (structure = round-10-verified enc kernel)
  __shared__ unsigned short As[128 * 64];
  __shared__ unsigned short Bs[128 * 64];
  const int tid = threadIdx.x;
  const int t = blockIdx.x - 64;     // 128 blocks
  const int k = t >> 4;
  const int rem = t & 15;
  const int row0 = (rem >> 2) * 128;  // e'
  const int col0 = (rem & 3) * 128;   // o

  const int lane = tid & 63, w = tid >> 6;
  const int wr = w >> 1, wc = w & 1;
  const int srow8 = tid >> 3;
  const int lslot = ((tid & 7) ^ (srow8 & 7)) * 8;
  const int ldsoff = tid * 8;
  const int r15 = lane & 15;
  const int qk = lane >> 4;
  const int rsw = r15 & 7;
  const int arow = wr * 64 + r15;
  const int brow = wc * 64 + r15;
  const unsigned short* Ak = AbfN + (size_t)k * ENCD * ENCD;

  f32x4 acc[4][4] = {};
  for (int k0 = 0; k0 < ENCD; k0 += 64) {
#pragma unroll
    for (int j = 0; j < 4; j++) {
      int row = j * 32 + srow8;
      gload_lds16(Ak + (size_t)(row0 + row) * ENCD + k0 + lslot, &As[j * 2048 + ldsoff]);
      gload_lds16(WbfT + (size_t)(col0 + row) * OBSD + k0 + lslot, &Bs[j * 2048 + ldsoff]);
    }
    __syncthreads();
#pragma unroll
    for (int kk = 0; kk < 2; kk++) {
      const int ps = ((kk * 4 + qk) ^ rsw) * 8;
      bf16x8 af[4], bfr[4];
#pragma unroll
      for (int m = 0; m < 4; m++) af[m] = *(const bf16x8*)&As[(arow + m * 16) * 64 + ps];
#pragma unroll
      for (int n = 0; n < 4; n++) bfr[n] = *(const bf16x8*)&Bs[(brow + n * 16) * 64 + ps];
#pragma unroll
      for (int m = 0; m < 4; m++)
#pragma unroll
        for (int n = 0; n < 4; n++)
          acc[m][n] = __builtin_amdgcn_mfma_f32_16x16x32_bf16(bfr[n], af[m], acc[m][n], 0, 0, 0);
    }
    __syncthreads();
  }
  unsigned short* Mk = MN + (size_t)k * ENCD * OBSD;
#pragma unroll
  for (int m = 0; m < 4; m++) {
    int rowg = row0 + wr * 64 + m * 16 + r15;
#pragma unroll
    for (int n = 0; n < 4; n++) {
      int colg = col0 + wc * 64 + n * 16 + qk * 4;
      uint2 v = {cvtpk(acc[m][n][0], acc[m][n][1]), cvtpk(acc[m][n][2], acc[m][n][3])};
      *(uint2*)&Mk[(size_t)rowg * OBSD + colg] = v;
    }
  }
}

// ---------------- grouped MFMA (r10 structure): acc = X1e - pred -----------
// 3 phases, BK=64 (17 iters): 8x {X1bf[rows] @ W}, 8x {X0bf[rows] @ M_kN},
// 1x {U[rows] @ BfTN}. Epilogue: loss += sum(acc^2).
__global__ __launch_bounds__(256, 2) void grouped_mfma_k(
    const unsigned short* __restrict__ X1bf, const unsigned short* __restrict__ X0bf,
    const unsigned short* __restrict__ Wbf, const unsigned short* __restrict__ Ubf,
    const unsigned short* __restrict__ MN, const unsigned short* __restrict__ BfTN,
    const int* __restrict__ rowlist, const int* __restrict__ counts,
    float* __restrict__ loss) {
  const int tid = threadIdx.x;
  const int bid = blockIdx.x;  // 4096 blocks
  const int lid = (bid & 7) * 512 + (bid >> 3);
  const int k = lid >> 9;
  const int rem = lid & 511;
  const int col0 = (rem & 3) * 128;
  const int tile = rem >> 2;

  int start = 0, cnt = 0;
#pragma unroll
  for (int j = 0; j < KEXP; j++) {
    int c = counts[j];
    if (j < k) start += c;
    if (j == k) cnt = c;
  }
  if (tile * 128 >= cnt) return;

  __shared__ unsigned short As[128 * 64];
  __shared__ unsigned short Bs[128 * 64];
  __shared__ int ridx[128];
  __shared__ float red[4];

  if (tid < 128) {
    int p = tile * 128 + tid;
    ridx[tid] = rowlist[start + (p < cnt ? p : 0)];
  }
  __syncthreads();

  const int lane = tid & 63, w = tid >> 6;
  const int wr = w >> 1, wc = w & 1;
  const int srow8 = tid >> 3;
  const int lslot = ((tid & 7) ^ (srow8 & 7)) * 8;
  const int ldsoff = tid * 8;
  const int r15 = lane & 15;
  const int qk = lane >> 4;
  const int rsw = r15 & 7;
  const int arow = wr * 64 + r15;
  const int brow = wc * 64 + r15;
  int rnj[4];
#pragma unroll
  for (int j = 0; j < 4; j++) rnj[j] = ridx[j * 32 + srow8];

  const unsigned short* MkN = MN + (size_t)k * ENCD * OBSD;
  const unsigned short* BfTkN = BfTN + (size_t)k * ENCD * ACTD;

  f32x4 acc[4][4] = {};
#define GROUPED_COMPUTE()                                                            \
  do {                                                                               \
    __syncthreads();                                                                 \
    _Pragma("unroll") for (int kk = 0; kk < 2; kk++) {                               \
      const int ps = ((kk * 4 + qk) ^ rsw) * 8;                                      \
      bf16x8 af[4], bfr[4];                                                          \
      _Pragma("unroll") for (int m = 0; m < 4; m++)                                  \
          af[m] = *(const bf16x8*)&As[(arow + m * 16) * 64 + ps];                    \
      _Pragma("unroll") for (int n = 0; n < 4; n++)                                  \
          bfr[n] = *(const bf16x8*)&Bs[(brow + n * 16) * 64 + ps];                   \
      _Pragma("unroll") for (int m = 0; m < 4; m++)                                  \
          _Pragma("unroll") for (int n = 0; n < 4; n++)                              \
              acc[m][n] = __builtin_amdgcn_mfma_f32_16x16x32_bf16(bfr[n], af[m],     \
                                                                  acc[m][n], 0, 0, 0); \
    }                                                                                \
    __syncthreads();                                                                 \
  } while (0)

  // phase 1: + X1bf[rows] @ W^T   (K = 512)
  for (int k0 = 0; k0 < OBSD; k0 += 64) {
#pragma unroll
    for (int j = 0; j < 4; j++) {
      int row = j * 32 + srow8;
      gload_lds16(X1bf + (size_t)rnj[j] * OBSD + k0 + lslot, &As[j * 2048 + ldsoff]);
      gload_lds16(Wbf + (size_t)(col0 + row) * OBSD + k0 + lslot, &Bs[j * 2048 + ldsoff]);
    }
    GROUPED_COMPUTE();
  }
  // phase 2: + X0bf[rows] @ M_kN^T   (K = 512)
  for (int k0 = 0; k0 < OBSD; k0 += 64) {
#pragma unroll
    for (int j = 0; j < 4; j++) {
      int row = j * 32 + srow8;
      gload_lds16(X0bf + (size_t)rnj[j] * OBSD + k0 + lslot, &As[j * 2048 + ldsoff]);
      gload_lds16(MkN + (size_t)(col0 + row) * OBSD + k0 + lslot, &Bs[j * 2048 + ldsoff]);
    }
    GROUPED_COMPUTE();
  }
  // phase 3: + U[rows] @ BfTN^T   (K = 64)
  {
#pragma unroll
    for (int j = 0; j < 4; j++) {
      int row = j * 32 + srow8;
      gload_lds16(Ubf + (size_t)rnj[j] * ACTD + lslot, &As[j * 2048 + ldsoff]);
      gload_lds16(BfTkN + (size_t)(col0 + row) * ACTD + lslot, &Bs[j * 2048 + ldsoff]);
    }
    GROUPED_COMPUTE();
  }
#undef GROUPED_COMPUTE

  // epilogue: acc holds X1e - pred; sum of squares over valid rows
  float sq = 0.f;
#pragma unroll
  for (int m = 0; m < 4; m++) {
    int lr = wr * 64 + m * 16 + r15;
    if (tile * 128 + lr < cnt) {
#pragma unroll
      for (int n = 0; n < 4; n++)
        sq += acc[m][n][0] * acc[m][n][0] + acc[m][n][1] * acc[m][n][1] +
              acc[m][n][2] * acc[m][n][2] + acc[m][n][3] * acc[m][n][3];
    }
  }
#pragma unroll
  for (int off = 32; off > 0; off >>= 1) sq += __shfl_xor(sq, off, 64);
  if (lane == 0) red[w] = sq;
  __syncthreads();
  if (tid == 0) atomicAdd(loss, red[0] + red[1] + red[2] + red[3]);
}

__global__ void finalize_k(const float* __restrict__ loss, float* __restrict__ out) {
  if (threadIdx.x == 0 && blockIdx.x == 0)
    out[0] = loss[0] * (1.0f / ((float)ENCD * (float)NROWS));
}

extern "C" void kernel_launch(void* const* d_in, const int* in_sizes, int n_in,
                              void* d_out, int out_size, void* d_ws, size_t ws_size,
                              hipStream_t stream) {
  const float* X1 = (const float*)d_in[0];
  const float* X0 = (const float*)d_in[1];
  const float* U = (const float*)d_in[2];
  const float* W = (const float*)d_in[3];
  const float* Aall = (const float*)d_in[4];
  const float* Brest = (const float*)d_in[5];
  const float* Cw = (const float*)d_in[6];
  const float* Cb = (const float*)d_in[7];
  float* out = (float*)d_out;

  char* p = (char*)d_ws;
  auto alloc = [&](size_t bytes) { char* r = p; p += (bytes + 255) & ~(size_t)255; return r; };
  unsigned short* X1bf = (unsigned short*)alloc((size_t)NROWS * OBSD * 2);
  unsigned short* X0bf = (unsigned short*)alloc((size_t)NROWS * OBSD * 2);
  unsigned short* Ubf = (unsigned short*)alloc((size_t)NROWS * ACTD * 2);
  unsigned short* Wbf = (unsigned short*)alloc((size_t)ENCD * OBSD * 2);
  unsigned short* AbfN = (unsigned short*)alloc((size_t)KEXP * ENCD * ENCD * 2);
  unsigned short* BfTN = (unsigned short*)alloc((size_t)KEXP * ENCD * ACTD * 2);
  unsigned short* WbfT = (unsigned short*)alloc((size_t)OBSD * ENCD * 2);
  unsigned short* MN = (unsigned short*)alloc((size_t)KEXP * ENCD * OBSD * 2);
  float* GT = (float*)alloc(KEXP * OBSD * 4);
  float* loss = (float*)alloc(256);
  int* inds = (int*)alloc(NROWS * 4);
  int* rowlist = (int*)alloc(NROWS * 4);
  int* counts = (int*)alloc(64);
  int* cursor = (int*)alloc(64);

  gt_k<<<64, 256, 0, stream>>>(W, Cw, GT, loss, counts, cursor);
  fused_prep_k<<<8057, 256, 0, stream>>>(X0, X1, U, W, Aall, Brest, GT, Cb,
                                         X0bf, X1bf, Ubf, Wbf, AbfN, BfTN,
                                         WbfT, inds, counts);
  scatmgemm_k<<<192, 256, 0, stream>>>(inds, counts, cursor, rowlist,
                                       AbfN, WbfT, MN);
  grouped_mfma_k<<<4096, 256, 0, stream>>>(X1bf, X0bf, Wbf, Ubf, MN, BfTN,
                                           rowlist, counts, loss);
  finalize_k<<<1, 64, 0, stream>>>(loss, out);
}